// Round 4
// baseline (4983.983 us; speedup 1.0000x reference)
//
#include <hip/hip_runtime.h>

// B=4, T=2048, C=1024, V=50257
// loss = mean_i [ log(sum_v exp(x_i.W_v + b_v)) - (x_i.W_{y_i} + b_{y_i}) ]
// R8: 256x256 LDS-staged fp8-MX GEMM, counted-vmcnt 3-buffer ring.
//  - R7's conflict-free packed span layout (verified: 0 bank conflicts)
//  - 3 x 32KB LDS buffers (96KB), depth-2 prefetch, vmcnt(4) steady state
//  - fully unrolled 16-kstep loop: all ring offsets compile-time, no peeled
//    duplicates, no sched_barrier -> arch VGPR must fit 128 (acc=128, cap 256)
//  - ONE s_barrier per kstep; s_setprio(1) around the 8-MFMA cluster

#define M_TOT 8192
#define K_TOT 1024
#define V_TOT 50257
#define NVB   197                // vocab blocks of 256
#define NPAD  (NVB * 256)        // 50432
#define PSTRIDE (NVB * 2)        // 394 partials per batch row
#define KB    (K_TOT / 64)       // 16 K-steps of 64
#define GSTRIDE ((long)KB * 64 * 32)   // bytes per packed 32-row group (32KB)

typedef __attribute__((ext_vector_type(8)))  int   int8v;
typedef __attribute__((ext_vector_type(16))) float floatx16;

__device__ __forceinline__ int f4_to_fp8x4(float4 v) {
  int r = __builtin_amdgcn_cvt_pk_fp8_f32(v.x, v.y, 0, false);
  r = __builtin_amdgcn_cvt_pk_fp8_f32(v.z, v.w, r, true);
  return r;
}

// Packed span layout (R7, verified conflict-free): span = (32-row group g,
// kstep kb), 2KB. MFMA lane l = h*32 + r needs operand bytes j=0..31 =
// fp8(src[g*32+r][kb*64 + h*32 + j]). 16B chunk (q*64 + l) holds operand
// bytes q*16..q*16+15 of lane l. Read: int4 lo at byte l*16, int4 hi at
// 1024 + l*16 -> both linear across lanes, conflict-free; identical pattern
// to the global_load_lds staging copy.
__global__ __launch_bounds__(256) void pack_kernel(
    const float* __restrict__ src, char* __restrict__ dst, int nrows) {
  const int kb = blockIdx.x, g = blockIdx.y;
  const int i = threadIdx.x;
  const int r = i >> 3, seg = i & 7;
  const int srow = g * 32 + r;
  int lo = 0, hi = 0;
  if (srow < nrows) {
    const float4* s = (const float4*)(src + (long)srow * K_TOT + kb * 64 + seg * 8);
    lo = f4_to_fp8x4(s[0]);
    hi = f4_to_fp8x4(s[1]);
  }
  const int h = seg >> 2;
  const int q = (seg >> 1) & 1;
  char* d = dst + ((long)(g * KB + kb) * 2048 +
                   (q * 64 + h * 32 + r) * 16 + (seg & 1) * 8);
  *(int2*)d = make_int2(lo, hi);
}

#define GLOAD16(gp, lp)                                              \
  __builtin_amdgcn_global_load_lds(                                  \
      (const __attribute__((address_space(1))) void*)(gp),           \
      (__attribute__((address_space(3))) void*)(lp), 16, 0, 0)

__device__ __forceinline__ int8v read_frag(const char* p) {
  int4 lo = *(const int4*)p;
  int4 hi = *(const int4*)(p + 1024);
  int8v r;
  r[0] = lo.x; r[1] = lo.y; r[2] = lo.z; r[3] = lo.w;
  r[4] = hi.x; r[5] = hi.y; r[6] = hi.z; r[7] = hi.w;
  return r;
}

// Block tile: 256 vocab x 256 batch, 8 waves (wv in 0..1 -> 128 vocab rows,
// wb in 0..3 -> 64 batch cols), per-wave 4x2 mfma_scale_f32_32x32x64 (unit
// scales = plain fp8). 16 ksteps, 3-buffer LDS ring, depth-2 prefetch.
__global__ __launch_bounds__(512, 2) void gemm_lse_kernel(
    const char* __restrict__ pW, const char* __restrict__ pX,
    const float* __restrict__ bias, float* __restrict__ psum) {
  __shared__ char sm[3][32768];   // per buf: A spans [0,16K), B spans [16K,32K)

  const int tid  = threadIdx.x;
  const int wid  = tid >> 6;
  const int lane = tid & 63;
  const int wv   = wid >> 2;           // vocab half (128 rows)
  const int wb   = wid & 3;            // batch quarter (64 cols)
  const int mblk = blockIdx.x;         // 0..31
  const int vblk = blockIdx.y;         // 0..196

  // per-lane global sources (lane*16 baked in); wave wid stages span wid
  const char* srcA = pW + (long)(vblk * 8 + wid) * GSTRIDE + lane * 16;
  const char* srcB = pX + (long)(mblk * 8 + wid) * GSTRIDE + lane * 16;
  // wave-uniform LDS staging dests (HW adds lane*16)
  char* dstA = &sm[0][0] + wid * 2048;
  char* dstB = &sm[0][0] + 16384 + wid * 2048;
  // per-lane LDS read bases
  const char* rdA = &sm[0][0] + (wv * 4) * 2048 + lane * 16;
  const char* rdB = &sm[0][0] + 16384 + (wb * 2) * 2048 + lane * 16;

  auto stage = [&](int t, int buf) {   // call sites pass literals only
    const int bo = buf * 32768;
    const long go = (long)t * 2048;
    GLOAD16(srcA + go,        dstA + bo);
    GLOAD16(srcA + go + 1024, dstA + bo + 1024);
    GLOAD16(srcB + go,        dstB + bo);
    GLOAD16(srcB + go + 1024, dstB + bo + 1024);
  };

  floatx16 acc[4][2] = {};

  // prologue: depth-2 prefetch (8 loads/wave outstanding)
  stage(0, 0);
  stage(1, 1);

  // steady state at kstep t entry: outstanding = stages {t, t+1} = 8 loads;
  // vmcnt(4) -> own stage-t landed; barrier -> all waves' stage-t landed.
#pragma unroll
  for (int t = 0; t < 16; ++t) {
    if (t < 15) { asm volatile("s_waitcnt vmcnt(4)" ::: "memory"); }
    else        { asm volatile("s_waitcnt vmcnt(0)" ::: "memory"); }
    __builtin_amdgcn_s_barrier();
    asm volatile("" ::: "memory");
    const int buf = t % 3;
    int8v a[4], b[2];
#pragma unroll
    for (int tn = 0; tn < 2; ++tn)
      b[tn] = read_frag(rdB + buf * 32768 + tn * 2048);
#pragma unroll
    for (int tv = 0; tv < 4; ++tv)
      a[tv] = read_frag(rdA + buf * 32768 + tv * 2048);
    if (t < 14) stage(t + 2, (t + 2) % 3);
    __builtin_amdgcn_s_setprio(1);
#pragma unroll
    for (int tv = 0; tv < 4; ++tv)
#pragma unroll
      for (int tn = 0; tn < 2; ++tn)
        acc[tv][tn] = __builtin_amdgcn_mfma_scale_f32_32x32x64_f8f6f4(
            a[tv], b[tn], acc[tv][tn], 0, 0, 0, 0x7F7F7F7F, 0, 0x7F7F7F7F);
    __builtin_amdgcn_s_setprio(0);
  }

  // Epilogue. C layout (verified R2/R3): col(batch) = l32,
  // row(vocab within 32-group) = (reg&3) + 8*(reg>>2) + 4*half.
  const int half = lane >> 5, l32 = lane & 31;
  const int vbase = vblk * 256 + wv * 128 + 4 * half;
  float s0 = 0.0f, s1 = 0.0f;
#pragma unroll
  for (int tv = 0; tv < 4; ++tv) {
#pragma unroll
    for (int reg = 0; reg < 16; ++reg) {
      int v = vbase + tv * 32 + (reg & 3) + 8 * (reg >> 2);
      float bv = (v < V_TOT) ? bias[v] : -1e30f;   // exp -> 0 for pad rows
      s0 += __expf(acc[tv][0][reg] + bv);
      s1 += __expf(acc[tv][1][reg] + bv);
    }
  }
  s0 += __shfl_xor(s0, 32, 64);
  s1 += __shfl_xor(s1, 32, 64);
  if (half == 0) {
    int m = mblk * 256 + wb * 64 + l32;
    long base = (long)m * PSTRIDE + vblk * 2 + wv;
    psum[base] = s0;                                // tn = 0
    psum[base + (long)32 * PSTRIDE] = s1;           // tn = 1 (m + 32)
  }
}

// One wave per batch row: sum 394 partials -> log; exact fp32 label logit.
__global__ __launch_bounds__(256) void finalize_kernel(
    const float* __restrict__ psum, const float* __restrict__ x,
    const float* __restrict__ W, const float* __restrict__ b,
    const int* __restrict__ y, float* __restrict__ loss) {
  const int wave = threadIdx.x >> 6;
  const int lane = threadIdx.x & 63;
  const int r = blockIdx.x * 4 + wave;

  const float* ps = psum + (long)r * PSTRIDE;
  float s = 0.0f;
  for (int j = lane; j < PSTRIDE; j += 64) s += ps[j];
#pragma unroll
  for (int o = 1; o < 64; o <<= 1) s += __shfl_xor(s, o, 64);

  int label = y[r];
  const float4* xr = (const float4*)(x + (long)r * K_TOT);
  const float4* wr = (const float4*)(W + (long)label * K_TOT);
  float d = 0.0f;
  for (int j = lane; j < K_TOT / 4; j += 64) {
    float4 a = xr[j], w = wr[j];
    d += a.x * w.x + a.y * w.y + a.z * w.z + a.w * w.w;
  }
#pragma unroll
  for (int o = 1; o < 64; o <<= 1) d += __shfl_xor(d, o, 64);

  if (lane == 0) loss[r] = logf(s) - d - b[label];
}

// Single block: deterministic mean of 8192 per-row losses.
__global__ __launch_bounds__(256) void reduce_kernel(
    const float* __restrict__ loss, float* __restrict__ out) {
  const int tid = threadIdx.x;
  float s = 0.0f;
  for (int j = tid; j < M_TOT; j += 256) s += loss[j];
#pragma unroll
  for (int o = 1; o < 64; o <<= 1) s += __shfl_xor(s, o, 64);
  __shared__ float wsum[4];
  if ((tid & 63) == 0) wsum[tid >> 6] = s;
  __syncthreads();
  if (tid == 0)
    out[0] = (wsum[0] + wsum[1] + wsum[2] + wsum[3]) * (1.0f / (float)M_TOT);
}

extern "C" void kernel_launch(void* const* d_in, const int* in_sizes, int n_in,
                              void* d_out, int out_size, void* d_ws, size_t ws_size,
                              hipStream_t stream) {
  (void)in_sizes; (void)n_in; (void)out_size; (void)ws_size;
  const float* x = (const float*)d_in[0];
  const int*   y = (const int*)d_in[1];
  const float* W = (const float*)d_in[2];
  const float* b = (const float*)d_in[3];
  float* out = (float*)d_out;

  char* ws = (char*)d_ws;
  const size_t PX_BYTES = (size_t)M_TOT * K_TOT;            // 8.4 MB
  const size_t PW_BYTES = (size_t)NPAD * K_TOT;             // 51.6 MB
  const size_t PS_BYTES = (size_t)M_TOT * PSTRIDE * 4;      // 12.9 MB
  char*  pX   = ws;
  char*  pW   = ws + PX_BYTES;
  float* psum = (float*)(ws + PX_BYTES + PW_BYTES);
  float* loss = (float*)(ws + PX_BYTES + PW_BYTES + PS_BYTES);

  pack_kernel<<<dim3(KB, M_TOT / 32), 256, 0, stream>>>(x, pX, M_TOT);
  pack_kernel<<<dim3(KB, NPAD / 32), 256, 0, stream>>>(W, pW, V_TOT);
  gemm_lse_kernel<<<dim3(M_TOT / 256, NVB), 512, 0, stream>>>(pW, pX, b, psum);
  finalize_kernel<<<M_TOT / 4, 256, 0, stream>>>(psum, x, W, b, y, loss);
  reduce_kernel<<<1, 256, 0, stream>>>(loss, out);
}

// Round 5
// 740.115 us; speedup vs baseline: 6.7341x; 6.7341x over previous
//
#include <hip/hip_runtime.h>

// B=4, T=2048, C=1024, V=50257
// loss = mean_i [ log(sum_v exp(x_i.W_v + b_v)) - (x_i.W_{y_i} + b_{y_i}) ]
// R9: 256x256 LDS-staged fp8-MX GEMM, counted-vmcnt 3-buffer ring,
//     SPILL-SAFE k-loop (R7/R8 regression root-caused to full unroll).
//  - R7 packed span layout (verified: 0 LDS bank conflicts)
//  - 3 x 32KB LDS ring (96KB), depth-2 prefetch, vmcnt(4) every kstep
//    (never drains in-loop); stage issued every kstep -> uniform invariant
//    (stages 16,17 read <=4KB past packed region, still in workspace, into
//    ring slots never read -> harmless)
//  - #pragma unroll 1 + pointer-increment addressing: only 2 addr pairs live
//    -> arch VGPR ~90 of 128 budget (acc=128, cap 256 @ 2 waves/SIMD)
//  - ONE s_barrier per kstep; s_setprio(1) around the 8-MFMA cluster

#define M_TOT 8192
#define K_TOT 1024
#define V_TOT 50257
#define NVB   197                // vocab blocks of 256
#define NPAD  (NVB * 256)        // 50432
#define PSTRIDE (NVB * 2)        // 394 partials per batch row
#define KB    (K_TOT / 64)       // 16 K-steps of 64
#define GSTRIDE ((long)KB * 64 * 32)   // bytes per packed 32-row group (32KB)

typedef __attribute__((ext_vector_type(8)))  int   int8v;
typedef __attribute__((ext_vector_type(16))) float floatx16;

__device__ __forceinline__ int f4_to_fp8x4(float4 v) {
  int r = __builtin_amdgcn_cvt_pk_fp8_f32(v.x, v.y, 0, false);
  r = __builtin_amdgcn_cvt_pk_fp8_f32(v.z, v.w, r, true);
  return r;
}

// Packed span layout (R7, verified conflict-free): span = (32-row group g,
// kstep kb), 2KB. MFMA lane l = h*32 + r needs operand bytes j=0..31 =
// fp8(src[g*32+r][kb*64 + h*32 + j]). 16B chunk (q*64 + l) holds operand
// bytes q*16..q*16+15 of lane l. Read: int4 lo at byte l*16, int4 hi at
// 1024 + l*16 -> both linear across lanes, conflict-free; identical pattern
// to the global_load_lds staging copy.
__global__ __launch_bounds__(256) void pack_kernel(
    const float* __restrict__ src, char* __restrict__ dst, int nrows) {
  const int kb = blockIdx.x, g = blockIdx.y;
  const int i = threadIdx.x;
  const int r = i >> 3, seg = i & 7;
  const int srow = g * 32 + r;
  int lo = 0, hi = 0;
  if (srow < nrows) {
    const float4* s = (const float4*)(src + (long)srow * K_TOT + kb * 64 + seg * 8);
    lo = f4_to_fp8x4(s[0]);
    hi = f4_to_fp8x4(s[1]);
  }
  const int h = seg >> 2;
  const int q = (seg >> 1) & 1;
  char* d = dst + ((long)(g * KB + kb) * 2048 +
                   (q * 64 + h * 32 + r) * 16 + (seg & 1) * 8);
  *(int2*)d = make_int2(lo, hi);
}

#define GLOAD16(gp, lp)                                              \
  __builtin_amdgcn_global_load_lds(                                  \
      (const __attribute__((address_space(1))) void*)(gp),           \
      (__attribute__((address_space(3))) void*)(lp), 16, 0, 0)

__device__ __forceinline__ int8v read_frag(const char* p) {
  int4 lo = *(const int4*)p;
  int4 hi = *(const int4*)(p + 1024);
  int8v r;
  r[0] = lo.x; r[1] = lo.y; r[2] = lo.z; r[3] = lo.w;
  r[4] = hi.x; r[5] = hi.y; r[6] = hi.z; r[7] = hi.w;
  return r;
}

// Block tile: 256 vocab x 256 batch, 8 waves (wv in 0..1 -> 128 vocab rows,
// wb in 0..3 -> 64 batch cols), per-wave 4x2 mfma_scale_f32_32x32x64 (unit
// scales = plain fp8). 16 ksteps, 3-buffer LDS ring, depth-2 prefetch.
__global__ __launch_bounds__(512, 2) void gemm_lse_kernel(
    const char* __restrict__ pW, const char* __restrict__ pX,
    const float* __restrict__ bias, float* __restrict__ psum) {
  __shared__ char sm[3][32768];   // per buf: A spans [0,16K), B spans [16K,32K)

  const int tid  = threadIdx.x;
  const int wid  = tid >> 6;
  const int lane = tid & 63;
  const int wv   = wid >> 2;           // vocab half (128 rows)
  const int wb   = wid & 3;            // batch quarter (64 cols)
  const int mblk = blockIdx.x;         // 0..31
  const int vblk = blockIdx.y;         // 0..196

  // walking global sources (lane*16 baked in); wave wid stages span wid.
  // advanced by 2048 per stage() call -> only 2 addr pairs ever live.
  const char* srcA = pW + (long)(vblk * 8 + wid) * GSTRIDE + lane * 16;
  const char* srcB = pX + (long)(mblk * 8 + wid) * GSTRIDE + lane * 16;

  // stage current srcA/srcB span into ring byte-offset o, then advance
  auto stage = [&](int o) {
    char* dA = &sm[0][0] + o + wid * 2048;           // wave-uniform dest
    char* dB = &sm[0][0] + o + 16384 + wid * 2048;   // (HW adds lane*16)
    GLOAD16(srcA,        dA);
    GLOAD16(srcA + 1024, dA + 1024);
    GLOAD16(srcB,        dB);
    GLOAD16(srcB + 1024, dB + 1024);
    srcA += 2048;
    srcB += 2048;
  };

  const int rdAoff = (wv * 4) * 2048 + lane * 16;           // + ring offset
  const int rdBoff = 16384 + (wb * 2) * 2048 + lane * 16;   // + ring offset

  floatx16 acc[4][2] = {};

  // prologue: depth-2 prefetch (8 loads/wave outstanding)
  stage(0);
  stage(32768);

  int curo = 0;        // ring offset being consumed
  int stgo = 65536;    // ring offset being staged (= consumed 2 ksteps later)
#pragma unroll 1
  for (int t = 0; t < 16; ++t) {
    // invariant at entry: outstanding = {stage t, stage t+1} = 8 loads;
    // vmcnt(4) -> own stage-t landed; barrier -> all waves' stage-t landed.
    asm volatile("s_waitcnt vmcnt(4)" ::: "memory");
    __builtin_amdgcn_s_barrier();
    asm volatile("" ::: "memory");
    const char* ba = &sm[0][0] + curo;
    int8v a[4], b[2];
#pragma unroll
    for (int tn = 0; tn < 2; ++tn) b[tn] = read_frag(ba + rdBoff + tn * 2048);
#pragma unroll
    for (int tv = 0; tv < 4; ++tv) a[tv] = read_frag(ba + rdAoff + tv * 2048);
    // stage kstep t+2 into buf (t+2)%3: its readers (iter t-1) finished
    // their ds_reads before the barrier above. Always staged (t=14,15 are
    // junk-but-in-workspace reads) to keep the vmcnt invariant branch-free.
    stage(stgo);
    __builtin_amdgcn_s_setprio(1);
#pragma unroll
    for (int tv = 0; tv < 4; ++tv)
#pragma unroll
      for (int tn = 0; tn < 2; ++tn)
        acc[tv][tn] = __builtin_amdgcn_mfma_scale_f32_32x32x64_f8f6f4(
            a[tv], b[tn], acc[tv][tn], 0, 0, 0, 0x7F7F7F7F, 0, 0x7F7F7F7F);
    __builtin_amdgcn_s_setprio(0);
    curo = (curo == 65536) ? 0 : curo + 32768;
    stgo = (stgo == 65536) ? 0 : stgo + 32768;
  }

  // Epilogue. C layout (verified R2/R3): col(batch) = l32,
  // row(vocab within 32-group) = (reg&3) + 8*(reg>>2) + 4*half.
  const int half = lane >> 5, l32 = lane & 31;
  const int vbase = vblk * 256 + wv * 128 + 4 * half;
  float s0 = 0.0f, s1 = 0.0f;
#pragma unroll
  for (int tv = 0; tv < 4; ++tv) {
#pragma unroll
    for (int reg = 0; reg < 16; ++reg) {
      int v = vbase + tv * 32 + (reg & 3) + 8 * (reg >> 2);
      float bv = (v < V_TOT) ? bias[v] : -1e30f;   // exp -> 0 for pad rows
      s0 += __expf(acc[tv][0][reg] + bv);
      s1 += __expf(acc[tv][1][reg] + bv);
    }
  }
  s0 += __shfl_xor(s0, 32, 64);
  s1 += __shfl_xor(s1, 32, 64);
  if (half == 0) {
    int m = mblk * 256 + wb * 64 + l32;
    long base = (long)m * PSTRIDE + vblk * 2 + wv;
    psum[base] = s0;                                // tn = 0
    psum[base + (long)32 * PSTRIDE] = s1;           // tn = 1 (m + 32)
  }
}

// One wave per batch row: sum 394 partials -> log; exact fp32 label logit.
__global__ __launch_bounds__(256) void finalize_kernel(
    const float* __restrict__ psum, const float* __restrict__ x,
    const float* __restrict__ W, const float* __restrict__ b,
    const int* __restrict__ y, float* __restrict__ loss) {
  const int wave = threadIdx.x >> 6;
  const int lane = threadIdx.x & 63;
  const int r = blockIdx.x * 4 + wave;

  const float* ps = psum + (long)r * PSTRIDE;
  float s = 0.0f;
  for (int j = lane; j < PSTRIDE; j += 64) s += ps[j];
#pragma unroll
  for (int o = 1; o < 64; o <<= 1) s += __shfl_xor(s, o, 64);

  int label = y[r];
  const float4* xr = (const float4*)(x + (long)r * K_TOT);
  const float4* wr = (const float4*)(W + (long)label * K_TOT);
  float d = 0.0f;
  for (int j = lane; j < K_TOT / 4; j += 64) {
    float4 a = xr[j], w = wr[j];
    d += a.x * w.x + a.y * w.y + a.z * w.z + a.w * w.w;
  }
#pragma unroll
  for (int o = 1; o < 64; o <<= 1) d += __shfl_xor(d, o, 64);

  if (lane == 0) loss[r] = logf(s) - d - b[label];
}

// Single block: deterministic mean of 8192 per-row losses.
__global__ __launch_bounds__(256) void reduce_kernel(
    const float* __restrict__ loss, float* __restrict__ out) {
  const int tid = threadIdx.x;
  float s = 0.0f;
  for (int j = tid; j < M_TOT; j += 256) s += loss[j];
#pragma unroll
  for (int o = 1; o < 64; o <<= 1) s += __shfl_xor(s, o, 64);
  __shared__ float wsum[4];
  if ((tid & 63) == 0) wsum[tid >> 6] = s;
  __syncthreads();
  if (tid == 0)
    out[0] = (wsum[0] + wsum[1] + wsum[2] + wsum[3]) * (1.0f / (float)M_TOT);
}

extern "C" void kernel_launch(void* const* d_in, const int* in_sizes, int n_in,
                              void* d_out, int out_size, void* d_ws, size_t ws_size,
                              hipStream_t stream) {
  (void)in_sizes; (void)n_in; (void)out_size; (void)ws_size;
  const float* x = (const float*)d_in[0];
  const int*   y = (const int*)d_in[1];
  const float* W = (const float*)d_in[2];
  const float* b = (const float*)d_in[3];
  float* out = (float*)d_out;

  char* ws = (char*)d_ws;
  const size_t PX_BYTES = (size_t)M_TOT * K_TOT;            // 8.4 MB
  const size_t PW_BYTES = (size_t)NPAD * K_TOT;             // 51.6 MB
  const size_t PS_BYTES = (size_t)M_TOT * PSTRIDE * 4;      // 12.9 MB
  char*  pX   = ws;
  char*  pW   = ws + PX_BYTES;
  float* psum = (float*)(ws + PX_BYTES + PW_BYTES);
  float* loss = (float*)(ws + PX_BYTES + PW_BYTES + PS_BYTES);

  pack_kernel<<<dim3(KB, M_TOT / 32), 256, 0, stream>>>(x, pX, M_TOT);
  pack_kernel<<<dim3(KB, NPAD / 32), 256, 0, stream>>>(W, pW, V_TOT);
  gemm_lse_kernel<<<dim3(M_TOT / 256, NVB), 512, 0, stream>>>(pW, pX, b, psum);
  finalize_kernel<<<M_TOT / 4, 256, 0, stream>>>(psum, x, W, b, y, loss);
  reduce_kernel<<<1, 256, 0, stream>>>(loss, out);
}